// Round 1
// baseline (101.849 us; speedup 1.0000x reference)
//
#include <hip/hip_runtime.h>
#include <math.h>

#define NB 4096
#define PI_F 3.14159265358979323846f
#define WT_FLOATS (784 * 12)   // transposed, padded W in d_ws

// ---------------------------------------------------------------------------
// Kernel 1: per-patch-position stats (mean, pi/(std+1e-6)) over the (B,4)
// slab, N=16384, unbiased (ddof=1). Also transposes W[10][784] into
// Wt[784][12] (pad 12 to keep later LDS b128 reads at uniform 8/bank).
// d_ws layout: [0, 9408) floats = Wt; [9408, 9800) floats = float2 stats[196].
// ---------------------------------------------------------------------------
__global__ __launch_bounds__(256) void k_stats(const float* __restrict__ x,
                                               const float* __restrict__ W,
                                               float* __restrict__ ws) {
    int p = blockIdx.x;            // 0..195
    int r = p / 14, c = p % 14;
    const float* base = x + r * 56 + c * 2;
    float s = 0.f, s2 = 0.f;
    for (int idx = threadIdx.x; idx < NB * 4; idx += 256) {
        int b = idx >> 2;
        int w = idx & 3;
        float v = base[b * 784 + (w >> 1) * 28 + (w & 1)];
        s += v;
        s2 = fmaf(v, v, s2);
    }
#pragma unroll
    for (int off = 32; off > 0; off >>= 1) {
        s  += __shfl_down(s, off, 64);
        s2 += __shfl_down(s2, off, 64);
    }
    __shared__ float red[8];
    int wave = threadIdx.x >> 6;
    if ((threadIdx.x & 63) == 0) { red[wave] = s; red[wave + 4] = s2; }
    __syncthreads();
    if (threadIdx.x == 0) {
        float S  = red[0] + red[1] + red[2] + red[3];
        float S2 = red[4] + red[5] + red[6] + red[7];
        const float N = (float)(NB * 4);
        float mean = S / N;
        float var = fmaxf((S2 - S * mean) / (N - 1.0f), 0.f);
        float scale = PI_F / (sqrtf(var) + 1e-6f);
        float2* stats = (float2*)(ws + WT_FLOATS);
        stats[p] = make_float2(mean, scale);
    }
    // W transpose: 7840 (f,o) pairs over 196 blocks = 40 per block
    if (threadIdx.x < 40) {
        int j = p * 40 + threadIdx.x;   // 0..7839
        int f = j / 10, o = j % 10;
        ws[f * 12 + o] = W[o * 784 + f];
    }
}

// ---------------------------------------------------------------------------
// Kernel 2: features + GEMV + log_softmax. 4 images per block, 1 per wave.
// Circuit reduced analytically: feats per patch p with pixels v0..v3:
//   [cos a0, cos a1, cos a0*cos a2, cos a1*cos a3],  a_w=(v_w-mean_p)*scale_p
// (RZ params provably cancel: diag*perm*diag*perm is monomial.)
// ---------------------------------------------------------------------------
__global__ __launch_bounds__(256) void k_main(const float* __restrict__ x,
                                              const float* __restrict__ bias,
                                              const float* __restrict__ ws,
                                              float* __restrict__ out) {
    __shared__ __align__(16) float  sWt[WT_FLOATS];   // 37632 B
    __shared__ __align__(16) float  sx[4 * 784];      // 12544 B
    __shared__ __align__(16) float2 sst[196];         // 1568 B

    const float4* wt4 = (const float4*)ws;
    for (int i = threadIdx.x; i < WT_FLOATS / 4; i += 256)
        ((float4*)sWt)[i] = wt4[i];
    const float4* st4 = (const float4*)(ws + WT_FLOATS);
    if (threadIdx.x < 98)
        ((float4*)sst)[threadIdx.x] = st4[threadIdx.x];
    const float4* x4 = (const float4*)(x + (size_t)blockIdx.x * 4 * 784);
    for (int i = threadIdx.x; i < 784; i += 256)
        ((float4*)sx)[i] = x4[i];
    __syncthreads();

    int wave = threadIdx.x >> 6;
    int lane = threadIdx.x & 63;
    const float* img = sx + wave * 784;

    float acc[10];
#pragma unroll
    for (int o = 0; o < 10; o++) acc[o] = 0.f;

    for (int k = 0; k < 13; k++) {
        int f = lane + 64 * k;
        if (f < 784) {
            int p = f >> 2, w = f & 3;
            int r = p / 14;
            int off = 2 * p + 28 * r + (w & 1);   // pixel addr within image
            float2 ms = sst[p];
            float feat = __cosf((img[off] - ms.x) * ms.y);
            if (w & 2) feat *= __cosf((img[off + 28] - ms.x) * ms.y);
            const float* wr = sWt + f * 12;
            float4 w0 = *(const float4*)wr;
            float4 w1 = *(const float4*)(wr + 4);
            float2 w2 = *(const float2*)(wr + 8);
            acc[0] = fmaf(feat, w0.x, acc[0]);
            acc[1] = fmaf(feat, w0.y, acc[1]);
            acc[2] = fmaf(feat, w0.z, acc[2]);
            acc[3] = fmaf(feat, w0.w, acc[3]);
            acc[4] = fmaf(feat, w1.x, acc[4]);
            acc[5] = fmaf(feat, w1.y, acc[5]);
            acc[6] = fmaf(feat, w1.z, acc[6]);
            acc[7] = fmaf(feat, w1.w, acc[7]);
            acc[8] = fmaf(feat, w2.x, acc[8]);
            acc[9] = fmaf(feat, w2.y, acc[9]);
        }
    }

#pragma unroll
    for (int o = 0; o < 10; o++) {
#pragma unroll
        for (int off = 32; off > 0; off >>= 1)
            acc[o] += __shfl_down(acc[o], off, 64);
    }

    if (lane == 0) {
        float m = -INFINITY;
#pragma unroll
        for (int o = 0; o < 10; o++) { acc[o] += bias[o]; m = fmaxf(m, acc[o]); }
        float ssum = 0.f;
#pragma unroll
        for (int o = 0; o < 10; o++) ssum += __expf(acc[o] - m);
        float lse = m + __logf(ssum);
        float* op = out + ((size_t)blockIdx.x * 4 + wave) * 10;
#pragma unroll
        for (int o = 0; o < 10; o++) op[o] = acc[o] - lse;
    }
}

extern "C" void kernel_launch(void* const* d_in, const int* in_sizes, int n_in,
                              void* d_out, int out_size, void* d_ws, size_t ws_size,
                              hipStream_t stream) {
    const float* x    = (const float*)d_in[0];
    // d_in[1] = params: provably unused (phases cancel in |amp|^2)
    const float* W    = (const float*)d_in[2];
    const float* bias = (const float*)d_in[3];
    float* ws  = (float*)d_ws;
    float* out = (float*)d_out;

    hipLaunchKernelGGL(k_stats, dim3(196), dim3(256), 0, stream, x, W, ws);
    hipLaunchKernelGGL(k_main, dim3(1024), dim3(256), 0, stream, x, bias, ws, out);
}

// Round 2
// 89.119 us; speedup vs baseline: 1.1428x; 1.1428x over previous
//
#include <hip/hip_runtime.h>
#include <math.h>

#define PI_F 3.14159265358979323846f

// d_ws layout: per-patch running sums, padded so each scalar owns a 64B line:
//   s  at ws[p*32], s2 at ws[p*32+16]   -> 196*32 floats = 25088 B (memset to 0)
#define SUMS_STRIDE 32
#define SUMS_BYTES (196 * SUMS_STRIDE * 4)

// ---------------------------------------------------------------------------
// Kernel 1: coalesced partial stats. 256 blocks x 16 images. Stage images as
// float4 (x read once from HBM, perfectly coalesced), 196 threads each own a
// patch position and reduce 64 LDS values, then 2 atomicAdds to padded slots.
// ---------------------------------------------------------------------------
__global__ __launch_bounds__(256) void k_partial(const float* __restrict__ x,
                                                 float* __restrict__ ws) {
    __shared__ __align__(16) float sx[16 * 784];   // 50176 B
    const float4* x4 = (const float4*)x;
    int base4 = blockIdx.x * (16 * 196);
    for (int i = threadIdx.x; i < 16 * 196; i += 256)
        ((float4*)sx)[i] = x4[base4 + i];
    __syncthreads();
    int p = threadIdx.x;
    if (p < 196) {
        int r = p / 14;
        int off = 2 * p + 28 * r;          // pixel (2r,2c) within an image
        float s = 0.f, s2 = 0.f;
#pragma unroll
        for (int i = 0; i < 16; i++) {
            const float* b = sx + i * 784 + off;
            float v0 = b[0], v1 = b[1], v2 = b[28], v3 = b[29];
            s += (v0 + v1) + (v2 + v3);
            s2 = fmaf(v0, v0, s2); s2 = fmaf(v1, v1, s2);
            s2 = fmaf(v2, v2, s2); s2 = fmaf(v3, v3, s2);
        }
        atomicAdd(ws + p * SUMS_STRIDE, s);
        atomicAdd(ws + p * SUMS_STRIDE + 16, s2);
    }
}

// ---------------------------------------------------------------------------
// Kernel 2: features + GEMV + log_softmax. 4 images/block, 1/wave.
// Circuit reduced analytically (RZ phases cancel; CNOTs permute basis):
//   feats = [cos a0, cos a1, cos a0*cos a2, cos a1*cos a3]
// W staged RAW [10][784]: lane f reads sW[o*784+f] -> stride-1, conflict-free.
// Stats finalized per-block from the 392 global sums (L2-hit, ~2 loads/thread).
// LDS = 31360 + 12544 + 1568 = 45472 B -> 3 blocks/CU, 12 waves/CU.
// ---------------------------------------------------------------------------
__global__ __launch_bounds__(256, 3) void k_main(const float* __restrict__ x,
                                                 const float* __restrict__ W,
                                                 const float* __restrict__ bias,
                                                 const float* __restrict__ ws,
                                                 float* __restrict__ out) {
    __shared__ __align__(16) float  sW[7840];     // raw W [10][784]
    __shared__ __align__(16) float  sx[4 * 784];
    __shared__ __align__(16) float2 sst[196];     // (mean, pi/(std+1e-6))

    const float4* W4 = (const float4*)W;
    for (int i = threadIdx.x; i < 1960; i += 256)
        ((float4*)sW)[i] = W4[i];
    const float4* x4 = (const float4*)(x + (size_t)blockIdx.x * 4 * 784);
    for (int i = threadIdx.x; i < 784; i += 256)
        ((float4*)sx)[i] = x4[i];
    if (threadIdx.x < 196) {
        int p = threadIdx.x;
        float s  = ws[p * SUMS_STRIDE];
        float s2 = ws[p * SUMS_STRIDE + 16];
        const float N = 16384.0f;
        float mean = s / N;
        float var = fmaxf((s2 - s * mean) / (N - 1.0f), 0.f);
        sst[p] = make_float2(mean, PI_F / (sqrtf(var) + 1e-6f));
    }
    __syncthreads();

    int wave = threadIdx.x >> 6;
    int lane = threadIdx.x & 63;
    const float* img = sx + wave * 784;

    float acc[10];
#pragma unroll
    for (int o = 0; o < 10; o++) acc[o] = 0.f;

    for (int k = 0; k < 13; k++) {
        int f = lane + 64 * k;
        if (f < 784) {
            int p = f >> 2, w = f & 3;
            int r = p / 14;
            int off = 2 * p + 28 * r + (w & 1);
            float2 ms = sst[p];
            float feat = __cosf((img[off] - ms.x) * ms.y);
            if (w & 2) feat *= __cosf((img[off + 28] - ms.x) * ms.y);
#pragma unroll
            for (int o = 0; o < 10; o++)
                acc[o] = fmaf(feat, sW[o * 784 + f], acc[o]);
        }
    }

#pragma unroll
    for (int o = 0; o < 10; o++) {
#pragma unroll
        for (int off = 32; off > 0; off >>= 1)
            acc[o] += __shfl_down(acc[o], off, 64);
    }

    if (lane == 0) {
        float m = -INFINITY;
#pragma unroll
        for (int o = 0; o < 10; o++) { acc[o] += bias[o]; m = fmaxf(m, acc[o]); }
        float ssum = 0.f;
#pragma unroll
        for (int o = 0; o < 10; o++) ssum += __expf(acc[o] - m);
        float lse = m + __logf(ssum);
        float* op = out + ((size_t)blockIdx.x * 4 + wave) * 10;
#pragma unroll
        for (int o = 0; o < 10; o++) op[o] = acc[o] - lse;
    }
}

extern "C" void kernel_launch(void* const* d_in, const int* in_sizes, int n_in,
                              void* d_out, int out_size, void* d_ws, size_t ws_size,
                              hipStream_t stream) {
    const float* x    = (const float*)d_in[0];
    // d_in[1] = params: provably unused (RZ phases cancel in |amp|^2)
    const float* W    = (const float*)d_in[2];
    const float* bias = (const float*)d_in[3];
    float* ws  = (float*)d_ws;
    float* out = (float*)d_out;

    hipMemsetAsync(ws, 0, SUMS_BYTES, stream);   // zero the atomic sum slots
    hipLaunchKernelGGL(k_partial, dim3(256), dim3(256), 0, stream, x, ws);
    hipLaunchKernelGGL(k_main, dim3(1024), dim3(256), 0, stream, x, W, bias, ws, out);
}